// Round 5
// baseline (1529.479 us; speedup 1.0000x reference)
//
#include <hip/hip_runtime.h>
#include <hip/hip_bf16.h>
#include <stdint.h>

// Problem constants
#define BB 4
#define SS 2048
#define HIDD 768
#define HH 12
#define DD 64
#define SCALE_F 0.125f
#define NQKV ((size_t)BB * SS * HIDD)   // 6,291,456
#define NW ((size_t)HIDD * HIDD)        // 589,824
#define NMW ((size_t)BB * SS * (SS / 64))

using bf16 = __hip_bfloat16;
typedef __attribute__((ext_vector_type(8))) short short8v;   // 8 bf16 (4 VGPRs)
typedef __attribute__((ext_vector_type(4))) float f32x4;     // MFMA accumulator
typedef __attribute__((ext_vector_type(4))) float fvec4;     // nontemporal-store safe
typedef __attribute__((ext_vector_type(4))) unsigned int uvec4;

// ---------- helpers ----------
__device__ __forceinline__ uint32_t bfb(float f) {
    bf16 h = __float2bfloat16(f);
    uint16_t u;
    __builtin_memcpy(&u, &h, 2);
    return (uint32_t)u;
}
__device__ __forceinline__ float b2f(uint32_t u) {
    uint32_t w = u << 16;
    float f;
    __builtin_memcpy(&f, &w, 4);
    return f;
}
__device__ __forceinline__ uint4 load8p(const float* p) {
    float4 a = *(const float4*)p;
    float4 b = *(const float4*)(p + 4);
    uint4 r;
    r.x = bfb(a.x) | (bfb(a.y) << 16);
    r.y = bfb(a.z) | (bfb(a.w) << 16);
    r.z = bfb(b.x) | (bfb(b.y) << 16);
    r.w = bfb(b.z) | (bfb(b.w) << 16);
    return r;
}
// combine two 8B halves (4 bf16 each) into one 16B A/B fragment
__device__ __forceinline__ short8v mk8(uint2 a, uint2 b) {
    union { short8v v; uint4 u; } x;
    x.u.x = a.x; x.u.y = a.y; x.u.z = b.x; x.u.w = b.y;
    return x.v;
}

// read one A/B fragment (8 bf16, 16B) from a swizzled tile (128B rows)
__device__ __forceinline__ short8v ldfrag(const char* base, int row, int bofs) {
    return *(const short8v*)(base + row * 128 + (bofs ^ ((row & 7) << 4)));
}

// async global->LDS DMA, 16B per lane. LDS dest is wave-uniform base + lane*16 (HW).
typedef __attribute__((address_space(1))) void as1_void;
typedef __attribute__((address_space(3))) void as3_void;
__device__ __forceinline__ void gload16(const void* g, void* l) {
    __builtin_amdgcn_global_load_lds((as1_void*)g, (as3_void*)l, 16, 0, 0);
}

// ---------- dtype detector (verified) ----------
__global__ void detect_kernel(const uint32_t* __restrict__ qraw,
                              const uint32_t* __restrict__ mraw,
                              int* __restrict__ flags) {
    __shared__ int ci, cn;
    int tid = threadIdx.x;
    if (tid == 0) { ci = 0; cn = 0; }
    __syncthreads();
    int li = 0;
    for (int l = 0; l < 8; l++) {
        uint32_t w = qraw[tid + l * 256];
        #pragma unroll
        for (int h = 0; h < 2; h++) {
            uint32_t bits = (h ? (w >> 16) : (w & 0xffffu)) << 16;
            float f = __uint_as_float(bits);
            float a = fabsf(f);
            if (a != 0.0f && (a > 1e3f || a < 1e-4f)) li++;
        }
    }
    int ln = 0;
    for (int l = 0; l < 4; l++) {
        if (mraw[tid + l * 256] > 1u) ln++;
    }
    atomicAdd(&ci, li);
    atomicAdd(&cn, ln);
    __syncthreads();
    if (tid == 0) {
        flags[0] = (ci > 1024) ? 0 : 1;  // 0 = fp32 tensors, 1 = bf16
        flags[1] = (cn > 64) ? 1 : 0;    // 1 = byte mask
    }
}

// ---------- bit-pack mask (verified) ----------
__global__ __launch_bounds__(256) void bitpack_mask(const int* __restrict__ flags,
                                                    const void* __restrict__ maskp,
                                                    uint64_t* __restrict__ mbits) {
    int gw = (int)((blockIdx.x * 256 + threadIdx.x) >> 6);
    int lane = threadIdx.x & 63;
    int byteM = flags[1];
    const int* mi = (const int*)maskp;
    const uint8_t* mb = (const uint8_t*)maskp;
    for (int it = 0; it < 64; it++) {
        size_t wi = (size_t)gw * 64 + it;
        size_t e = wi * 64 + lane;
        int m = byteM ? (int)mb[e] : mi[e];
        unsigned long long b = __ballot(m != 0);
        if (lane == 0) mbits[wi] = (uint64_t)b;
    }
}

// ---------- convert Q/K/V to packed bf16 ----------
__global__ __launch_bounds__(256) void convert_in(const int* __restrict__ flags,
                                                  const void* __restrict__ Q,
                                                  const void* __restrict__ K,
                                                  const void* __restrict__ V,
                                                  bf16* __restrict__ xb) {
    int isbf = flags[0];
    int z = blockIdx.y;
    const void* src = (z == 0) ? Q : (z == 1) ? K : V;
    size_t base = ((size_t)blockIdx.x * 256 + threadIdx.x) * 8;
    bf16* dst = xb + (size_t)z * NQKV + base;
    if (isbf) {
        *(uint4*)dst = *(const uint4*)((const bf16*)src + base);
    } else {
        *(uint4*)dst = load8p((const float*)src + base);
    }
}

// ---------- convert 4 biases to fp32 ----------
__global__ void convert_bias(const int* __restrict__ flags,
                             const void* __restrict__ b0, const void* __restrict__ b1,
                             const void* __restrict__ b2, const void* __restrict__ b3,
                             float* __restrict__ bf) {
    int isbf = flags[0];
    for (int i = threadIdx.x; i < 4 * HIDD; i += 256) {
        int z = i / HIDD, j = i - z * HIDD;
        const void* b = (z == 0) ? b0 : (z == 1) ? b1 : (z == 2) ? b2 : b3;
        bf[i] = isbf ? b2f((uint32_t) * ((const uint16_t*)b + j)) : ((const float*)b)[j];
    }
}

// ---------- transpose weights: W[768k][768n] -> WT bf16 [z][768n][768k] ----------
__global__ __launch_bounds__(256) void transpose_w2(const int* __restrict__ flags,
                                                    const void* __restrict__ W0,
                                                    const void* __restrict__ W1,
                                                    const void* __restrict__ W2,
                                                    const void* __restrict__ W3,
                                                    bf16* __restrict__ WT) {
    int isbf = flags[0];
    __shared__ uint16_t tb[64][65];
    int tid = threadIdx.x;
    int z = blockIdx.z;
    const void* W = (z == 0) ? W0 : (z == 1) ? W1 : (z == 2) ? W2 : W3;
    int k0 = blockIdx.y * 64, n0 = blockIdx.x * 64;
    #pragma unroll
    for (int l = 0; l < 16; l++) {
        int idx = tid + l * 256;
        int r = idx >> 6, c = idx & 63;
        size_t off = (size_t)(k0 + r) * HIDD + n0 + c;
        tb[c][r] = isbf ? *((const uint16_t*)W + off) : (uint16_t)bfb(((const float*)W)[off]);
    }
    __syncthreads();
    bf16* dst = WT + (size_t)z * NW;
    #pragma unroll
    for (int l = 0; l < 16; l++) {
        int idx = tid + l * 256;
        int r = idx >> 6, c = idx & 63;
        *(uint16_t*)&dst[(size_t)(n0 + r) * HIDD + k0 + c] = tb[r][c];
    }
}

// ---------- MFMA GEMM v3: DMA-staged, Y = X @ WT^T + biasf, grid.z batches ----------
template <int HSPLIT>
__global__ __launch_bounds__(256) void gemm3(const int* __restrict__ flags,
                                             const bf16* __restrict__ X,
                                             const bf16* __restrict__ WT,
                                             const float* __restrict__ biasf,
                                             bf16* __restrict__ Yh,
                                             float* __restrict__ Yf,
                                             bf16* __restrict__ Yb) {
    int z = blockIdx.z;
    X += (size_t)z * NQKV;
    WT += (size_t)z * NW;
    biasf += (size_t)z * HIDD;
    if (HSPLIT) Yh += (size_t)z * NQKV;
    __shared__ char xs[128 * 128];
    __shared__ char ws[64 * 128];
    int tid = threadIdx.x;
    int lane = tid & 63, w = tid >> 6;
    int g = lane >> 4, t = lane & 15;
    int row0 = blockIdx.y * 128, n0 = blockIdx.x * 64;
    const f32x4 fz = {0.f, 0.f, 0.f, 0.f};
    f32x4 acc[2][4];
    #pragma unroll
    for (int rb = 0; rb < 2; rb++)
        #pragma unroll
        for (int c = 0; c < 4; c++) acc[rb][c] = fz;
    int r8 = tid >> 3, c8 = tid & 7;
    const char* Xb0 = (const char*)(X + (size_t)row0 * HIDD);
    const char* Wb0 = (const char*)(WT + (size_t)n0 * HIDD);
    for (int kt = 0; kt < HIDD; kt += 64) {
        #pragma unroll
        for (int i = 0; i < 4; i++) {
            int r = r8 + i * 32;
            gload16(Xb0 + (size_t)r * (HIDD * 2) + kt * 2 + ((c8 * 16) ^ ((r & 7) << 4)),
                    xs + w * 1024 + i * 4096);
        }
        #pragma unroll
        for (int i = 0; i < 2; i++) {
            int r = r8 + i * 32;
            gload16(Wb0 + (size_t)r * (HIDD * 2) + kt * 2 + ((c8 * 16) ^ ((r & 7) << 4)),
                    ws + w * 1024 + i * 4096);
        }
        __syncthreads();   // drains vmcnt(0) -> DMA complete
        #pragma unroll
        for (int ks = 0; ks < 2; ks++) {
            short8v a0 = ldfrag(xs, w * 32 + t, g * 16 + ks * 64);
            short8v a1 = ldfrag(xs, w * 32 + 16 + t, g * 16 + ks * 64);
            #pragma unroll
            for (int c = 0; c < 4; c++) {
                short8v b = ldfrag(ws, c * 16 + t, g * 16 + ks * 64);
                acc[0][c] = __builtin_amdgcn_mfma_f32_16x16x32_bf16(a0, b, acc[0][c], 0, 0, 0);
                acc[1][c] = __builtin_amdgcn_mfma_f32_16x16x32_bf16(a1, b, acc[1][c], 0, 0, 0);
            }
        }
        __syncthreads();
    }
    int isbf = flags[0];
    #pragma unroll
    for (int c = 0; c < 4; c++) {
        int col = n0 + c * 16 + t;
        float bv = biasf[col];
        #pragma unroll
        for (int rb = 0; rb < 2; rb++) {
            #pragma unroll
            for (int r = 0; r < 4; r++) {
                int row = row0 + w * 32 + rb * 16 + g * 4 + r;
                float v = acc[rb][c][r] + bv;
                if (HSPLIT) {
                    int b_ = row >> 11, s = row & 2047, h2 = col >> 6, d = col & 63;
                    Yh[(((size_t)b_ * HH + h2) * SS + s) * DD + d] = __float2bfloat16(v);
                } else {
                    if (isbf) Yb[(size_t)row * HIDD + col] = __float2bfloat16(v);
                    else      Yf[(size_t)row * HIDD + col] = v;
                }
            }
        }
    }
}

// ---------- transpose V: vh [bh][s][64] -> vt [bh][64][2048] (verified) ----------
__global__ __launch_bounds__(256) void transpose_v(const bf16* __restrict__ vh,
                                                   bf16* __restrict__ vt) {
    __shared__ uint16_t tb[64][65];
    int tid = threadIdx.x;
    int s0 = blockIdx.x * 64, bh = blockIdx.y;
    const bf16* src = vh + ((size_t)bh * SS + s0) * DD;
    #pragma unroll
    for (int i = 0; i < 2; i++) {
        int u = tid + (i << 8);
        int r = u >> 3, sg = u & 7;
        uint4 v = *(const uint4*)(src + (size_t)r * DD + sg * 8);
        uint32_t wv[4] = {v.x, v.y, v.z, v.w};
        #pragma unroll
        for (int j = 0; j < 4; j++) {
            tb[r][sg * 8 + 2 * j]     = (uint16_t)(wv[j] & 0xffffu);
            tb[r][sg * 8 + 2 * j + 1] = (uint16_t)(wv[j] >> 16);
        }
    }
    __syncthreads();
    bf16* dst = vt + (size_t)bh * DD * SS + s0;
    #pragma unroll
    for (int i = 0; i < 2; i++) {
        int u = tid + (i << 8);
        int d = u >> 3, sg = u & 7;
        uint32_t w0 = (uint32_t)tb[sg * 8 + 0][d] | ((uint32_t)tb[sg * 8 + 1][d] << 16);
        uint32_t w1 = (uint32_t)tb[sg * 8 + 2][d] | ((uint32_t)tb[sg * 8 + 3][d] << 16);
        uint32_t w2 = (uint32_t)tb[sg * 8 + 4][d] | ((uint32_t)tb[sg * 8 + 5][d] << 16);
        uint32_t w3 = (uint32_t)tb[sg * 8 + 6][d] | ((uint32_t)tb[sg * 8 + 7][d] << 16);
        uint4 o; o.x = w0; o.y = w1; o.z = w2; o.w = w3;
        *(uint4*)(dst + (size_t)d * SS + sg * 8) = o;
    }
}

// ---------- fused attention v4: swapped QK^T, ZERO barriers in main loop ----------
// mfma(K,Q) puts P[q=lane&15][k = w*16+g*4+r] lane-local: each wave owns k-slice
// [w*16, w*16+16) of every 64-tile, computes its own partial PV over that slice,
// and partial O's are reduced once at the end. P (unnormalized exp, bf16) goes to
// LDS only for the final normalized write-out. 2 sub-tiles (128 k) per iteration
// so PV can use the verified 16x16x32 intrinsic (8 k-values/lane A-frag).
__global__ __launch_bounds__(256) void fused_attn4(const int* __restrict__ flags,
                                                   const bf16* __restrict__ qh,
                                                   const bf16* __restrict__ kh,
                                                   const bf16* __restrict__ vt,
                                                   const uint64_t* __restrict__ mbits,
                                                   float* __restrict__ Pf,
                                                   bf16* __restrict__ Ph,
                                                   bf16* __restrict__ ctx) {
    const int isf32 = (flags[0] == 0);
    __shared__ char pl[16 * 4096];   // P tile 16q x 2048k bf16, swizzled; reused as ored
    __shared__ float red[4][16];
    __shared__ float invl[16];
    int tid = threadIdx.x;
    int lane = tid & 63, w = tid >> 6;
    int g = lane >> 4, t = lane & 15;
    int q0 = blockIdx.x * 16, bh = blockIdx.y;
    int b_ = bh / HH, h = bh - b_ * HH;
    const f32x4 fz = {0.f, 0.f, 0.f, 0.f};
    int sh = w * 16 + g * 4;          // lane's k-offset within a 64-tile

    // Q B-fragments: row = q = t, k-dim = d = g*8+i (+32)
    const bf16* qbase = qh + ((size_t)bh * SS + q0 + t) * DD;
    short8v bq0 = *(const short8v*)(qbase + g * 8);
    short8v bq1 = *(const short8v*)(qbase + 32 + g * 8);

    // K A-fragment base: row = k = ts + w*16 + t, d = g*8 (+32)
    const bf16* kb = kh + ((size_t)bh * SS + w * 16 + t) * DD + g * 8;
    // V^T fragment base: row d = t (+db*16), k = ts + w*16 + g*4
    const bf16* vbr = vt + ((size_t)bh * DD + t) * SS + sh;
    const uint64_t* mrow = mbits + ((size_t)b_ * SS + q0 + t) * (SS / 64);

    // preload iteration 0
    short8v cK00 = *(const short8v*)(kb);
    short8v cK01 = *(const short8v*)(kb + 32);
    short8v cK10 = *(const short8v*)(kb + 64 * DD);
    short8v cK11 = *(const short8v*)(kb + 64 * DD + 32);
    uint4 cMM = *(const uint4*)(mrow);
    uint2 cV[4][2];
    #pragma unroll
    for (int db = 0; db < 4; db++) {
        cV[db][0] = *(const uint2*)(vbr + (size_t)db * 16 * SS);
        cV[db][1] = *(const uint2*)(vbr + (size_t)db * 16 * SS + 64);
    }

    float sum = 0.f;
    f32x4 o[4] = {fz, fz, fz, fz};

    for (int it = 0; it < 16; ++it) {
        // ---- prefetch next iteration (wrapped on last; values unused) ----
        int ni = (it + 1) & 15;
        const bf16* knb = kb + (size_t)ni * 128 * DD;
        short8v nK00 = *(const short8v*)(knb);
        short8v nK01 = *(const short8v*)(knb + 32);
        short8v nK10 = *(const short8v*)(knb + 64 * DD);
        short8v nK11 = *(const short8v*)(knb + 64 * DD + 32);
        uint4 nMM = *(const uint4*)(mrow + ni * 2);
        uint2 nV[4][2];
        #pragma unroll
        for (int db = 0; db < 4; db++) {
            nV[db][0] = *(const uint2*)(vbr + (size_t)db * 16 * SS + ni * 128);
            nV[db][1] = *(const uint2*)(vbr + (size_t)db * 16 * SS + ni * 128 + 64);
        }

        // ---- QK^T (swapped): D[m=k-local g*4+r][n=q=t] ----
        f32x4 s0 = fz, s1 = fz;
        s0 = __builtin_amdgcn_mfma_f32_16x16x32_bf16(cK00, bq0, s0, 0, 0, 0);
        s0 = __builtin_amdgcn_mfma_f32_16x16x32_bf16(cK01, bq1, s0, 0, 0, 0);
        s1 = __builtin_amdgcn_mfma_f32_16x16x32_bf16(cK10, bq0, s1, 0, 0, 0);
        s1 = __builtin_amdgcn_mfma_f32_16x16x32_bf16(cK11, bq1, s1, 0, 0, 0);

        // ---- mask + exp + row-sum (q = t is lane-fixed) ----
        uint64_t M0 = ((uint64_t)cMM.y << 32) | cMM.x;
        uint64_t M1 = ((uint64_t)cMM.w << 32) | cMM.z;
        uint32_t mb0 = (uint32_t)(M0 >> sh) & 0xFu;
        uint32_t mb1 = (uint32_t)(M1 >> sh) & 0xFu;
        float p0[4], p1[4];
        #pragma unroll
        for (int r = 0; r < 4; r++) {
            float sv0 = ((mb0 >> r) & 1u) ? -1e30f : s0[r] * SCALE_F;
            p0[r] = __expf(fminf(sv0, 30.0f));
            float sv1 = ((mb1 >> r) & 1u) ? -1e30f : s1[r] * SCALE_F;
            p1[r] = __expf(fminf(sv1, 30.0f));
            sum += p0[r] + p1[r];
        }

        // ---- pack P -> bf16; stash to pl (disjoint bytes per wave, no barrier) ----
        uint2 pw0, pw1;
        pw0.x = bfb(p0[0]) | (bfb(p0[1]) << 16);
        pw0.y = bfb(p0[2]) | (bfb(p0[3]) << 16);
        pw1.x = bfb(p1[0]) | (bfb(p1[1]) << 16);
        pw1.y = bfb(p1[2]) | (bfb(p1[3]) << 16);
        int ts0 = it * 128;
        int k0b = (ts0 + sh) * 2, k1b = (ts0 + 64 + sh) * 2;
        *(uint2*)(pl + t * 4096 + (k0b ^ ((t & 7) << 4))) = pw0;
        *(uint2*)(pl + t * 4096 + (k1b ^ ((t & 7) << 4))) = pw1;

        // ---- PV partial over this wave's 32 k (16 from each sub-tile) ----
        short8v pa = mk8(pw0, pw1);
        #pragma unroll
        for (int db = 0; db < 4; db++) {
            o[db] = __builtin_amdgcn_mfma_f32_16x16x32_bf16(pa, mk8(cV[db][0], cV[db][1]),
                                                            o[db], 0, 0, 0);
        }

        // rotate prefetch
        cK00 = nK00; cK01 = nK01; cK10 = nK10; cK11 = nK11;
        cMM = nMM;
        #pragma unroll
        for (int db = 0; db < 4; db++) { cV[db][0] = nV[db][0]; cV[db][1] = nV[db][1]; }
    }

    // ---- l reduce: over g-groups (same q=t), then over waves ----
    float sg = sum;
    sg += __shfl_xor(sg, 16);
    sg += __shfl_xor(sg, 32);
    if (lane < 16) red[w][lane] = sg;
    __syncthreads();
    if (tid < 16) {
        float tot = red[0][tid] + red[1][tid] + red[2][tid] + red[3][tid];
        invl[tid] = (tot > 0.f) ? 1.0f / tot : 0.0f;
    }
    __syncthreads();

    // ---- normalized P write-out (coalesced, nontemporal) ----
    int prow = tid >> 4, cg = tid & 15;
    float pinv = invl[prow];
    size_t rowb = ((size_t)bh * SS + q0 + prow) * SS;
    if (isf32) {
        #pragma unroll
        for (int c0 = 0; c0 < SS; c0 += 128) {
            int col = c0 + cg * 8;
            uint4 pv = *(const uint4*)(pl + prow * 4096 + ((col * 2) ^ ((prow & 7) << 4)));
            fvec4 lo = {b2f(pv.x & 0xffffu) * pinv, b2f(pv.x >> 16) * pinv,
                        b2f(pv.y & 0xffffu) * pinv, b2f(pv.y >> 16) * pinv};
            fvec4 hi = {b2f(pv.z & 0xffffu) * pinv, b2f(pv.z >> 16) * pinv,
                        b2f(pv.w & 0xffffu) * pinv, b2f(pv.w >> 16) * pinv};
            __builtin_nontemporal_store(lo, (fvec4*)(Pf + rowb + col));
            __builtin_nontemporal_store(hi, (fvec4*)(Pf + rowb + col + 4));
        }
    } else {
        #pragma unroll
        for (int c0 = 0; c0 < SS; c0 += 128) {
            int col = c0 + cg * 8;
            uint4 pv = *(const uint4*)(pl + prow * 4096 + ((col * 2) ^ ((prow & 7) << 4)));
            uvec4 ov;
            ov.x = bfb(b2f(pv.x & 0xffffu) * pinv) | (bfb(b2f(pv.x >> 16) * pinv) << 16);
            ov.y = bfb(b2f(pv.y & 0xffffu) * pinv) | (bfb(b2f(pv.y >> 16) * pinv) << 16);
            ov.z = bfb(b2f(pv.z & 0xffffu) * pinv) | (bfb(b2f(pv.z >> 16) * pinv) << 16);
            ov.w = bfb(b2f(pv.w & 0xffffu) * pinv) | (bfb(b2f(pv.w >> 16) * pinv) << 16);
            __builtin_nontemporal_store(ov, (uvec4*)(Ph + rowb + col));
        }
    }
    __syncthreads();

    // ---- cross-wave O reduction through pl (reused as [w][16q][65] f32) ----
    float* ored = (float*)pl;
    #pragma unroll
    for (int db = 0; db < 4; db++)
        #pragma unroll
        for (int r = 0; r < 4; r++)
            ored[(w * 16 + g * 4 + r) * 65 + db * 16 + t] = o[db][r];
    __syncthreads();
    int qq = tid >> 4, d4 = (tid & 15) * 4;
    float iv = invl[qq];
    float cj[4];
    #pragma unroll
    for (int j = 0; j < 4; j++) {
        cj[j] = (ored[(0 * 16 + qq) * 65 + d4 + j] + ored[(1 * 16 + qq) * 65 + d4 + j] +
                 ored[(2 * 16 + qq) * 65 + d4 + j] + ored[(3 * 16 + qq) * 65 + d4 + j]) * iv;
    }
    uint2 cw;
    cw.x = bfb(cj[0]) | (bfb(cj[1]) << 16);
    cw.y = bfb(cj[2]) | (bfb(cj[3]) << 16);
    *(uint2*)&ctx[((size_t)b_ * SS + q0 + qq) * HIDD + h * DD + d4] = cw;
}

extern "C" void kernel_launch(void* const* d_in, const int* in_sizes, int n_in,
                              void* d_out, int out_size, void* d_ws, size_t ws_size,
                              hipStream_t stream) {
    // workspace: qh, kh, vh(=ctx), vt (bf16), WT[4] (bf16), mbits, flags, biasf
    bf16* qh = (bf16*)d_ws;
    bf16* kh = qh + NQKV;
    bf16* vh = kh + NQKV;
    bf16* vt = vh + NQKV;
    bf16* WT = vt + NQKV;
    uint64_t* mbits = (uint64_t*)(WT + 4 * NW);
    int* flags = (int*)(mbits + NMW);
    float* bfp = (float*)(flags + 4);
    bf16* ctx = vh;  // vh dead after transpose_v

    // xb (converted bf16 Q,K,V) lives inside d_out's P region (written only at the
    // very end by fused_attn4; xb consumed by the projection GEMMs before that).
    bf16* xb = (bf16*)((char*)d_out + NQKV * 4);

    detect_kernel<<<1, 256, 0, stream>>>((const uint32_t*)d_in[0], (const uint32_t*)d_in[3], flags);
    bitpack_mask<<<1024, 256, 0, stream>>>(flags, d_in[3], mbits);
    convert_in<<<dim3(3072, 3), 256, 0, stream>>>(flags, d_in[0], d_in[1], d_in[2], xb);
    convert_bias<<<1, 256, 0, stream>>>(flags, d_in[5], d_in[7], d_in[9], d_in[11], bfp);
    transpose_w2<<<dim3(12, 12, 4), 256, 0, stream>>>(flags, d_in[4], d_in[6], d_in[8],
                                                      d_in[10], WT);

    dim3 blk(256);
    dim3 gG(HIDD / 64, (BB * SS) / 128, 3);  // QKV batched in z
    dim3 gO(HIDD / 64, (BB * SS) / 128, 1);
    dim3 gT(SS / 64, BB * HH);               // (32, 48)
    dim3 gF(SS / 16, BB * HH);               // (128, 48)

    // Q,K,V projections in one launch (z = 0,1,2); outputs qh,kh,vh contiguous
    gemm3<1><<<gG, blk, 0, stream>>>(flags, xb, WT, bfp, qh, nullptr, nullptr);

    transpose_v<<<gT, blk, 0, stream>>>(vh, vt);

    fused_attn4<<<gF, blk, 0, stream>>>(flags, qh, kh, vt, mbits,
                                        (float*)d_out + NQKV, (bf16*)d_out + NQKV, ctx);

    // output projection (z = 0 offsets are no-ops; pass Wo/bo slot 3 directly)
    gemm3<0><<<gO, blk, 0, stream>>>(flags, ctx, WT + 3 * NW, bfp + 3 * HIDD,
                                     nullptr, (float*)d_out, (bf16*)d_out);
}